// Round 9
// baseline (334.477 us; speedup 1.0000x reference)
//
#include <hip/hip_runtime.h>
#include <math.h>

#define WS_ 8
#define NH_ 8
#define C_ 256
#define B_ 8
#define M_ 32768            // B_*L_
#define SH_ 4               // WS_/2
#define LN_EPS 1e-5f
#define SL_ 8388608         // elements per [M,C] slot

typedef __attribute__((ext_vector_type(8))) short bf16x8;
typedef __attribute__((ext_vector_type(4))) float f32x4;

__device__ inline float b2f(unsigned short u) {
    union { unsigned int i; float f; } c; c.i = ((unsigned int)u) << 16; return c.f;
}
__device__ inline unsigned short f2b(float f) {
    union { unsigned int i; float f; } c; c.f = f;
    unsigned int u = c.i;
    return (unsigned short)((u + 0x7FFFu + ((u >> 16) & 1u)) >> 16);
}
__device__ inline float gelu_f(float x) {
    // tanh-form GELU: x * sigmoid(1.59576912*(x + 0.044715 x^3)); |err| < ~1e-3
    float t = 1.59576912160573f * (x + 0.044715f * x * x * x);
    return x / (1.f + __expf(-t));
}

// ---------------- AdaLN: ss = t_embed @ w + b --------------------------------
__global__ void adaln_k(const float* __restrict__ te,
                        const float* __restrict__ w1, const float* __restrict__ b1,
                        const float* __restrict__ w2, const float* __restrict__ b2,
                        float* __restrict__ ss1, float* __restrict__ ss2) {
    int t = blockIdx.x * 256 + threadIdx.x;          // 0..8191
    int which = t >> 12;
    int rem = t & 4095;
    int b = rem >> 9;
    int col = rem & 511;
    const float* w = which ? w2 : w1;
    const float* bb = which ? b2 : b1;
    const float* tr = te + b * C_;
    float acc = bb[col];
    for (int k = 0; k < C_; ++k) acc += tr[k] * w[k * 512 + col];
    (which ? ss2 : ss1)[b * 512 + col] = acc;
}

// ---------- weight prep: bf16 [N][K] transposes, qkv bias, bias_full ---------
__global__ void prep_k(const float* __restrict__ qw, const float* __restrict__ kw,
                       const float* __restrict__ vw, const float* __restrict__ ow,
                       const float* __restrict__ f1w, const float* __restrict__ f2w,
                       const float* __restrict__ qb, const float* __restrict__ kb,
                       const float* __restrict__ vb, const float* __restrict__ bt,
                       unsigned short* __restrict__ qkvT, unsigned short* __restrict__ oT,
                       unsigned short* __restrict__ f1T, unsigned short* __restrict__ f2T,
                       float* __restrict__ qkvB, float* __restrict__ bias_full) {
    int t = blockIdx.x * 256 + threadIdx.x;
    if (t < 196608) {                       // qkvT [768][256]
        int n = t >> 8, k = t & 255;
        const float* w = n < 256 ? qw : (n < 512 ? kw : vw);
        qkvT[t] = f2b(w[k * 256 + (n & 255)]);
    } else if (t < 262144) {                // oT [256][256]
        int i = t - 196608; int n = i >> 8, k = i & 255;
        oT[i] = f2b(ow[k * 256 + n]);
    } else if (t < 524288) {                // f1T [1024][256]
        int i = t - 262144; int n = i >> 8, k = i & 255;
        f1T[i] = f2b(f1w[k * 1024 + n]);
    } else if (t < 786432) {                // f2T [256][1024]
        int i = t - 524288; int n = i >> 10, k = i & 1023;
        f2T[i] = f2b(f2w[k * 256 + n]);
    } else if (t < 787200) {                // qkv bias [768]
        int i = t - 786432;
        qkvB[i] = i < 256 ? qb[i] : (i < 512 ? kb[i - 256] : vb[i - 512]);
    } else if (t < 787200 + 32768) {        // bias_full [8][64][64]
        int i = t - 787200;
        int head = i >> 12, qk = i & 4095;
        int q = qk >> 6, k = qk & 63;
        int qh = q >> 3, qw2 = q & 7, kh = k >> 3, kw2 = k & 7;
        bias_full[i] = bt[((qh - kh + 7) * 15 + (qw2 - kw2 + 7)) * 8 + head];
    }
}

// ------ LN + modulate + shift + window partition: one wave per token ---------
__global__ __launch_bounds__(256) void ln_win_k(const float* __restrict__ x,
                                                const float* __restrict__ ss,
                                                unsigned short* __restrict__ xw) {
    int t = blockIdx.x * 4 + (threadIdx.x >> 6);     // token 0..32767
    int lane = threadIdx.x & 63;
    int b = t >> 12, rem = t & 4095;
    int hg = rem >> 6, wg = rem & 63;
    int hs = (hg + SH_) & 63, wsrc = (wg + SH_) & 63;
    size_t src = ((size_t)b << 12) + (hs << 6) + wsrc;
    float4 v = *(const float4*)&x[src * C_ + lane * 4];
    float s = v.x + v.y + v.z + v.w;
    float s2 = v.x * v.x + v.y * v.y + v.z * v.z + v.w * v.w;
#pragma unroll
    for (int m = 1; m < 64; m <<= 1) { s += __shfl_xor(s, m); s2 += __shfl_xor(s2, m); }
    float mu = s * (1.f / 256.f);
    float rstd = rsqrtf(s2 * (1.f / 256.f) - mu * mu + LN_EPS);
    float4 sc = *(const float4*)&ss[b * 512 + lane * 4];
    float4 sh = *(const float4*)&ss[b * 512 + 256 + lane * 4];
    int win = (b << 6) + ((hg >> 3) << 3) + (wg >> 3);
    int pos = ((hg & 7) << 3) + (wg & 7);
    ushort4 pk;
    pk.x = f2b((v.x - mu) * rstd * (1.f + sc.x) + sh.x);
    pk.y = f2b((v.y - mu) * rstd * (1.f + sc.y) + sh.y);
    pk.z = f2b((v.z - mu) * rstd * (1.f + sc.z) + sh.z);
    pk.w = f2b((v.w - mu) * rstd * (1.f + sc.w) + sh.w);
    *(ushort4*)(xw + (size_t)(win * 64 + pos) * C_ + lane * 4) = pk;
}

// ---------------- LN + modulate: one wave per token --------------------------
__global__ __launch_bounds__(256) void ln_k(const float* __restrict__ x,
                                            const float* __restrict__ ss,
                                            unsigned short* __restrict__ y_out) {
    int t = blockIdx.x * 4 + (threadIdx.x >> 6);
    int lane = threadIdx.x & 63;
    int b = t >> 12;
    float4 v = *(const float4*)&x[(size_t)t * C_ + lane * 4];
    float s = v.x + v.y + v.z + v.w;
    float s2 = v.x * v.x + v.y * v.y + v.z * v.z + v.w * v.w;
#pragma unroll
    for (int m = 1; m < 64; m <<= 1) { s += __shfl_xor(s, m); s2 += __shfl_xor(s2, m); }
    float mu = s * (1.f / 256.f);
    float rstd = rsqrtf(s2 * (1.f / 256.f) - mu * mu + LN_EPS);
    float4 sc = *(const float4*)&ss[b * 512 + lane * 4];
    float4 sh = *(const float4*)&ss[b * 512 + 256 + lane * 4];
    ushort4 pk;
    pk.x = f2b((v.x - mu) * rstd * (1.f + sc.x) + sh.x);
    pk.y = f2b((v.y - mu) * rstd * (1.f + sc.y) + sh.y);
    pk.z = f2b((v.z - mu) * rstd * (1.f + sc.z) + sh.z);
    pk.w = f2b((v.w - mu) * rstd * (1.f + sc.w) + sh.w);
    *(ushort4*)(y_out + (size_t)t * C_ + lane * 4) = pk;
}

// ------ A-stream / B-in-registers GEMM for K=256, N-per-wave=32 --------------
// No LDS, no barriers. Wave w owns 32 N-cols (16 resident B-frags); all 4
// waves stream ALL 16 slabs (16 rows each) of the block's 256-row M-group,
// A-frags straight from global (layout == MFMA A-frag), next slab prefetched.
// Grid: blk -> xcd=blk&7, idx=blk>>3, nt=idx>>4, mg=xcd+((idx&15)<<3).
// MODE 0: QKV -> permuted bf16 [which][win][head][pos][d] + bias
// MODE 2: FFN1 -> gelu, bf16 out [M][1024]
template <int MODE>
__global__ __launch_bounds__(256, 2) void gemm_as_k(
    const unsigned short* __restrict__ A, const unsigned short* __restrict__ Bt,
    const float* __restrict__ bias, unsigned short* __restrict__ Cout) {
    const int blk = blockIdx.x;
    const int xcd = blk & 7, idx = blk >> 3;
    const int nt = idx >> 4;
    const int mg = xcd + ((idx & 15) << 3);          // 0..127, 256 rows each
    const int w = threadIdx.x >> 6, lane = threadIdx.x & 63;
    const int quad = lane >> 4, l16 = lane & 15;
    const int n0 = nt * 128 + w * 32;

    // B fragments, resident for the whole kernel
    bf16x8 bfr[2][8];
#pragma unroll
    for (int j = 0; j < 2; ++j) {
        const unsigned short* bp = Bt + (size_t)(n0 + j * 16 + l16) * 256 + quad * 8;
#pragma unroll
        for (int k = 0; k < 8; ++k) bfr[j][k] = *(const bf16x8*)(bp + k * 32);
    }
    float4 bv[2];
#pragma unroll
    for (int j = 0; j < 2; ++j) bv[j] = *(const float4*)&bias[n0 + j * 16 + quad * 4];

    int m0 = mg * 256;
    const unsigned short* ap = A + (size_t)(m0 + l16) * 256 + quad * 8;
    bf16x8 af[8];
#pragma unroll
    for (int k = 0; k < 8; ++k) af[k] = *(const bf16x8*)(ap + k * 32);

    for (int s = 0; s < 16; ++s) {
        // prefetch next slab (clamped on last iter; values unused then)
        const unsigned short* apn = ap + (s < 15 ? (size_t)16 * 256 : 0);
        bf16x8 afn[8];
#pragma unroll
        for (int k = 0; k < 8; ++k) afn[k] = *(const bf16x8*)(apn + k * 32);

        f32x4 acc[2] = {};
#pragma unroll
        for (int k = 0; k < 8; ++k) {
            acc[0] = __builtin_amdgcn_mfma_f32_16x16x32_bf16(bfr[0][k], af[k], acc[0], 0, 0, 0);
            acc[1] = __builtin_amdgcn_mfma_f32_16x16x32_bf16(bfr[1][k], af[k], acc[1], 0, 0, 0);
        }

        const int row = m0 + l16;
        if (MODE == 0) {
            int win = row >> 6, pos = row & 63;
            size_t rowbase = (size_t)win * 16384 + pos * 32;
#pragma unroll
            for (int j = 0; j < 2; ++j) {
                int col = n0 + j * 16 + quad * 4;
                int which = col >> 8, head = (col >> 5) & 7, dc = col & 31;
                ushort4 pk = {f2b(acc[j][0] + bv[j].x), f2b(acc[j][1] + bv[j].y),
                              f2b(acc[j][2] + bv[j].z), f2b(acc[j][3] + bv[j].w)};
                *(ushort4*)(Cout + (size_t)which * SL_ + rowbase + head * 2048 + dc) = pk;
            }
        } else {
            size_t rb = (size_t)row * 1024;
#pragma unroll
            for (int j = 0; j < 2; ++j) {
                int col = n0 + j * 16 + quad * 4;
                ushort4 pk = {f2b(gelu_f(acc[j][0] + bv[j].x)), f2b(gelu_f(acc[j][1] + bv[j].y)),
                              f2b(gelu_f(acc[j][2] + bv[j].z)), f2b(gelu_f(acc[j][3] + bv[j].w))};
                *(ushort4*)(Cout + rb + col) = pk;
            }
        }
        m0 += 16;
        ap += (size_t)16 * 256;
#pragma unroll
        for (int k = 0; k < 8; ++k) af[k] = afn[k];
    }
}

// --------------- bf16 MFMA GEMM, 128x128 tile, BK=64, swizzled LDS -----------
// (R7 structure; used for O-proj MODE 1 and FFN2 MODE 3.)
template <int KDIM, int MODE, int NT>
__global__ __launch_bounds__(256, 4) void gemm_bf16_k(
    const unsigned short* __restrict__ A, const unsigned short* __restrict__ Bt,
    const float* __restrict__ bias, const float* __restrict__ res,
    void* __restrict__ Cout, int Nout) {
    __shared__ __align__(16) unsigned short As[2][128 * 32];
    __shared__ __align__(16) unsigned short Bs[2][128 * 32];
    const int blk = blockIdx.x;
    const int xcd = blk & 7;
    const int idx = blk >> 3;
    const int mt = xcd + ((idx / NT) << 3);
    const int nt = idx % NT;
    const int bm = mt * 128, bn = nt * 128;
    const int tid = threadIdx.x;
    const int w = tid >> 6, lane = tid & 63;
    const int quad = lane >> 4, l16 = lane & 15;
    const int wm = (w >> 1) * 64, wn = (w & 1) * 64;
    const int srow = lane >> 2;
    const int qlog = ((lane & 3) ^ ((lane >> 3) & 3)) << 3;
    const int rsw = ((l16 >> 1) & 3) << 3;

    f32x4 acc[4][4] = {};

    for (int k0 = 0; k0 < KDIM; k0 += 64) {
        if (k0) __syncthreads();
#pragma unroll
        for (int h = 0; h < 2; ++h) {
#pragma unroll
            for (int j = 0; j < 2; ++j) {
                int r = j * 64 + w * 16 + srow;
                const unsigned short* ga = A + (size_t)(bm + r) * KDIM + k0 + h * 32 + qlog;
                unsigned short* la = &As[h][j * 2048 + w * 512 + lane * 8];
                __builtin_amdgcn_global_load_lds(
                    (const __attribute__((address_space(1))) void*)ga,
                    (__attribute__((address_space(3))) void*)la, 16, 0, 0);
                const unsigned short* gb = Bt + (size_t)(bn + r) * KDIM + k0 + h * 32 + qlog;
                unsigned short* lb = &Bs[h][j * 2048 + w * 512 + lane * 8];
                __builtin_amdgcn_global_load_lds(
                    (const __attribute__((address_space(1))) void*)gb,
                    (__attribute__((address_space(3))) void*)lb, 16, 0, 0);
            }
        }
        __syncthreads();
#pragma unroll
        for (int h = 0; h < 2; ++h) {
            bf16x8 af[4], bfr[4];
#pragma unroll
            for (int i = 0; i < 4; ++i)
                af[i] = *(const bf16x8*)&As[h][(wm + i * 16 + l16) * 32 + ((quad << 3) ^ rsw)];
#pragma unroll
            for (int j = 0; j < 4; ++j)
                bfr[j] = *(const bf16x8*)&Bs[h][(wn + j * 16 + l16) * 32 + ((quad << 3) ^ rsw)];
#pragma unroll
            for (int i = 0; i < 4; ++i)
#pragma unroll
                for (int j = 0; j < 4; ++j)
                    acc[i][j] = __builtin_amdgcn_mfma_f32_16x16x32_bf16(
                        bfr[j], af[i], acc[i][j], 0, 0, 0);
        }
    }

#pragma unroll
    for (int i = 0; i < 4; ++i) {
        const int row = bm + wm + i * 16 + l16;
        size_t rowbase = 0;
        if (MODE == 1) {
            int win = row >> 6, pos = row & 63;
            int b = win >> 6, wh = (win >> 3) & 7, ww = win & 7;
            int hg = (wh << 3) + (pos >> 3), wg = (ww << 3) + (pos & 7);
            int hd = (hg + SH_) & 63, wd = (wg + SH_) & 63;
            rowbase = (((size_t)b << 12) + (hd << 6) + wd) * C_;
        } else {
            rowbase = (size_t)row * Nout;
        }
#pragma unroll
        for (int j = 0; j < 4; ++j) {
            const int col = bn + wn + j * 16 + quad * 4;
            float4 bv = *(const float4*)&bias[col];
            float v0 = acc[i][j][0] + bv.x, v1 = acc[i][j][1] + bv.y;
            float v2 = acc[i][j][2] + bv.z, v3 = acc[i][j][3] + bv.w;
            float4 rv = *(const float4*)&res[rowbase + col];
            float4 ov = {v0 + rv.x, v1 + rv.y, v2 + rv.z, v3 + rv.w};
            *(float4*)&((float*)Cout)[rowbase + col] = ov;
        }
    }
}

// ------------- MFMA window attention: one wave per (window, head) ------------
__global__ __launch_bounds__(256) void attn_mfma_k(
    const unsigned short* __restrict__ qkv, const float* __restrict__ bias_full,
    unsigned short* __restrict__ attn_out) {
    __shared__ __align__(16) unsigned short Pb[4][64 * 66];
    __shared__ __align__(16) unsigned short Vt[4][32 * 66];
    const int w = threadIdx.x >> 6, lane = threadIdx.x & 63;
    const int wh = blockIdx.x * 4 + w;        // 0..4095
    const int win = wh >> 3, head = wh & 7;
    const int quad = lane >> 4, l16 = lane & 15;

    const unsigned short* qp = qkv + (size_t)win * 16384 + head * 2048;
    const unsigned short* kp = qp + SL_;
    const unsigned short* vp = qp + 2 * (size_t)SL_;

    // stage V transposed: Vt[d][pos]
    {
        const uint4* v4 = (const uint4*)(vp + lane * 32);
        unsigned short* dst = &Vt[w][0];
#pragma unroll
        for (int c = 0; c < 4; ++c) {
            uint4 u = v4[c];
            unsigned int uu[4] = {u.x, u.y, u.z, u.w};
#pragma unroll
            for (int p = 0; p < 4; ++p) {
                int d0 = c * 8 + p * 2;
                dst[d0 * 66 + lane] = (unsigned short)(uu[p] & 0xffff);
                dst[(d0 + 1) * 66 + lane] = (unsigned short)(uu[p] >> 16);
            }
        }
    }

    bf16x8 qf[4], kf[4];
#pragma unroll
    for (int i = 0; i < 4; ++i) {
        qf[i] = *(const bf16x8*)(qp + (i * 16 + l16) * 32 + quad * 8);
        kf[i] = *(const bf16x8*)(kp + (i * 16 + l16) * 32 + quad * 8);
    }

    f32x4 s[4][4] = {};
#pragma unroll
    for (int i = 0; i < 4; ++i)
#pragma unroll
        for (int j = 0; j < 4; ++j)
            s[i][j] = __builtin_amdgcn_mfma_f32_16x16x32_bf16(qf[i], kf[j], s[i][j], 0, 0, 0);

    const float scale = 0.17677669529663687f;
    const float* bf = bias_full + head * 4096;
    float rs[4][4];
#pragma unroll
    for (int i = 0; i < 4; ++i) {
#pragma unroll
        for (int r = 0; r < 4; ++r) {
            int row = i * 16 + quad * 4 + r;
            float acc = 0.f;
#pragma unroll
            for (int j = 0; j < 4; ++j) {
                float e = __expf(s[i][j][r] * scale + bf[row * 64 + j * 16 + l16]);
                s[i][j][r] = e;
                acc += e;
            }
#pragma unroll
            for (int msk = 1; msk < 16; msk <<= 1) acc += __shfl_xor(acc, msk);
            rs[i][r] = 1.f / acc;
        }
    }

#pragma unroll
    for (int i = 0; i < 4; ++i)
#pragma unroll
        for (int j = 0; j < 4; ++j)
#pragma unroll
            for (int r = 0; r < 4; ++r)
                Pb[w][(i * 16 + quad * 4 + r) * 66 + j * 16 + l16] = f2b(s[i][j][r]);

    __syncthreads();

    f32x4 o[4][2] = {};
#pragma unroll
    for (int st = 0; st < 2; ++st) {
        bf16x8 bv[2];
#pragma unroll
        for (int jo = 0; jo < 2; ++jo)
            bv[jo] = *(const bf16x8*)&Vt[w][(jo * 16 + l16) * 66 + st * 32 + quad * 8];
#pragma unroll
        for (int i = 0; i < 4; ++i) {
            bf16x8 af = *(const bf16x8*)&Pb[w][(i * 16 + l16) * 66 + st * 32 + quad * 8];
#pragma unroll
            for (int jo = 0; jo < 2; ++jo)
                o[i][jo] = __builtin_amdgcn_mfma_f32_16x16x32_bf16(af, bv[jo], o[i][jo], 0, 0, 0);
        }
    }

#pragma unroll
    for (int i = 0; i < 4; ++i)
#pragma unroll
        for (int jo = 0; jo < 2; ++jo)
#pragma unroll
            for (int r = 0; r < 4; ++r) {
                int row = i * 16 + quad * 4 + r;
                int d = jo * 16 + l16;
                attn_out[((size_t)(win * 64 + row)) * C_ + head * 32 + d] =
                    f2b(o[i][jo][r] * rs[i][r]);
            }
}

extern "C" void kernel_launch(void* const* d_in, const int* in_sizes, int n_in,
                              void* d_out, int out_size, void* d_ws, size_t ws_size,
                              hipStream_t stream) {
    const float* x        = (const float*)d_in[0];
    const float* t_embed  = (const float*)d_in[1];
    const float* adaln1_w = (const float*)d_in[4];
    const float* adaln1_b = (const float*)d_in[5];
    const float* adaln2_w = (const float*)d_in[6];
    const float* adaln2_b = (const float*)d_in[7];
    const float* bt       = (const float*)d_in[8];
    const float* q_w = (const float*)d_in[9],  *q_b = (const float*)d_in[10];
    const float* k_w = (const float*)d_in[11], *k_b = (const float*)d_in[12];
    const float* v_w = (const float*)d_in[13], *v_b = (const float*)d_in[14];
    const float* o_w = (const float*)d_in[15], *o_b = (const float*)d_in[16];
    const float* f1_w = (const float*)d_in[17], *f1_b = (const float*)d_in[18];
    const float* f2_w = (const float*)d_in[19], *f2_b = (const float*)d_in[20];
    float* out = (float*)d_out;

    char* wsb = (char*)d_ws;
    float* ss1            = (float*)(wsb + 0);
    float* ss2            = (float*)(wsb + 16384);
    float* qkvB           = (float*)(wsb + 32768);
    unsigned short* qkvT  = (unsigned short*)(wsb + 36864);
    unsigned short* oT    = (unsigned short*)(wsb + 430080);
    unsigned short* f1T   = (unsigned short*)(wsb + 561152);
    unsigned short* f2T   = (unsigned short*)(wsb + 1085440);
    float* bias_full      = (float*)(wsb + 1609728);               // 131072 B
    unsigned short* xw    = (unsigned short*)(wsb + 2097152);      // [M][256] bf16
    unsigned short* qkv   = (unsigned short*)(wsb + 18874368);     // 3 x SL_ bf16
    unsigned short* attn  = (unsigned short*)(wsb + 69206016);     // [M][256] bf16
    unsigned short* xn2   = xw;                                    // reuse
    unsigned short* hbuf  = qkv;                                   // reuse (67.1 MB)
    float* x1             = (float*)(wsb + 85983232);              // [M][256] fp32

    prep_k<<<3203, 256, 0, stream>>>(q_w, k_w, v_w, o_w, f1_w, f2_w, q_b, k_b, v_b, bt,
                                     qkvT, oT, f1T, f2T, qkvB, bias_full);
    adaln_k<<<32, 256, 0, stream>>>(t_embed, adaln1_w, adaln1_b, adaln2_w, adaln2_b, ss1, ss2);
    ln_win_k<<<8192, 256, 0, stream>>>(x, ss1, xw);

    gemm_as_k<0><<<768, 256, 0, stream>>>(xw, qkvT, qkvB, qkv);          // QKV (N=768)

    attn_mfma_k<<<1024, 256, 0, stream>>>(qkv, bias_full, attn);

    gemm_bf16_k<256, 1, 2><<<512, 256, 0, stream>>>(attn, oT, o_b, x, x1, 256);
    ln_k<<<8192, 256, 0, stream>>>(x1, ss2, xn2);
    gemm_as_k<2><<<1024, 256, 0, stream>>>(xn2, f1T, f1_b, hbuf);        // FFN1 (N=1024)
    gemm_bf16_k<1024, 3, 2><<<512, 256, 0, stream>>>(hbuf, f2T, f2_b, x1, out, 256);
}

// Round 10
// 270.749 us; speedup vs baseline: 1.2354x; 1.2354x over previous
//
#include <hip/hip_runtime.h>
#include <math.h>

#define WS_ 8
#define NH_ 8
#define C_ 256
#define B_ 8
#define M_ 32768            // B_*L_
#define SH_ 4               // WS_/2
#define LN_EPS 1e-5f
#define SL_ 8388608         // elements per [M,C] slot

typedef __attribute__((ext_vector_type(8))) short bf16x8;
typedef __attribute__((ext_vector_type(4))) float f32x4;

__device__ inline float b2f(unsigned short u) {
    union { unsigned int i; float f; } c; c.i = ((unsigned int)u) << 16; return c.f;
}
__device__ inline unsigned short f2b(float f) {
    union { unsigned int i; float f; } c; c.f = f;
    unsigned int u = c.i;
    return (unsigned short)((u + 0x7FFFu + ((u >> 16) & 1u)) >> 16);
}
__device__ inline float gelu_f(float x) {
    // tanh-form GELU: x * sigmoid(1.59576912*(x + 0.044715 x^3)); |err| < ~1e-3
    float t = 1.59576912160573f * (x + 0.044715f * x * x * x);
    return x / (1.f + __expf(-t));
}

// ---------- weight prep + adaln fused: bf16 [N][K] transposes, qkv bias,
// ---------- bias_full, and ss = t_embed @ w + b for both adaln layers -------
__global__ void prep_k(const float* __restrict__ qw, const float* __restrict__ kw,
                       const float* __restrict__ vw, const float* __restrict__ ow,
                       const float* __restrict__ f1w, const float* __restrict__ f2w,
                       const float* __restrict__ qb, const float* __restrict__ kb,
                       const float* __restrict__ vb, const float* __restrict__ bt,
                       const float* __restrict__ te,
                       const float* __restrict__ a1w, const float* __restrict__ a1b,
                       const float* __restrict__ a2w, const float* __restrict__ a2b,
                       unsigned short* __restrict__ qkvT, unsigned short* __restrict__ oT,
                       unsigned short* __restrict__ f1T, unsigned short* __restrict__ f2T,
                       float* __restrict__ qkvB, float* __restrict__ bias_full,
                       float* __restrict__ ss1, float* __restrict__ ss2) {
    int t = blockIdx.x * 256 + threadIdx.x;
    if (t < 196608) {                       // qkvT [768][256]
        int n = t >> 8, k = t & 255;
        const float* w = n < 256 ? qw : (n < 512 ? kw : vw);
        qkvT[t] = f2b(w[k * 256 + (n & 255)]);
    } else if (t < 262144) {                // oT [256][256]
        int i = t - 196608; int n = i >> 8, k = i & 255;
        oT[i] = f2b(ow[k * 256 + n]);
    } else if (t < 524288) {                // f1T [1024][256]
        int i = t - 262144; int n = i >> 8, k = i & 255;
        f1T[i] = f2b(f1w[k * 1024 + n]);
    } else if (t < 786432) {                // f2T [256][1024]
        int i = t - 524288; int n = i >> 10, k = i & 1023;
        f2T[i] = f2b(f2w[k * 256 + n]);
    } else if (t < 787200) {                // qkv bias [768]
        int i = t - 786432;
        qkvB[i] = i < 256 ? qb[i] : (i < 512 ? kb[i - 256] : vb[i - 512]);
    } else if (t < 819968) {                // bias_full [8][64][64]
        int i = t - 787200;
        int head = i >> 12, qk = i & 4095;
        int q = qk >> 6, k = qk & 63;
        int qh = q >> 3, qw2 = q & 7, kh = k >> 3, kw2 = k & 7;
        bias_full[i] = bt[((qh - kh + 7) * 15 + (qw2 - kw2 + 7)) * 8 + head];
    } else if (t < 828160) {                // adaln: 2 x [8][512]
        int i = t - 819968;
        int which = i >> 12;
        int rem = i & 4095;
        int b = rem >> 9, col = rem & 511;
        const float* w = which ? a2w : a1w;
        const float* bb = which ? a2b : a1b;
        const float* tr = te + b * C_;
        float acc = bb[col];
        for (int k = 0; k < C_; ++k) acc += tr[k] * w[k * 512 + col];
        (which ? ss2 : ss1)[b * 512 + col] = acc;
    }
}

// ------ LN + modulate + shift + window partition: one wave per token ---------
__global__ __launch_bounds__(256) void ln_win_k(const float* __restrict__ x,
                                                const float* __restrict__ ss,
                                                unsigned short* __restrict__ xw) {
    int t = blockIdx.x * 4 + (threadIdx.x >> 6);     // token 0..32767
    int lane = threadIdx.x & 63;
    int b = t >> 12, rem = t & 4095;
    int hg = rem >> 6, wg = rem & 63;
    int hs = (hg + SH_) & 63, wsrc = (wg + SH_) & 63;
    size_t src = ((size_t)b << 12) + (hs << 6) + wsrc;
    float4 v = *(const float4*)&x[src * C_ + lane * 4];
    float s = v.x + v.y + v.z + v.w;
    float s2 = v.x * v.x + v.y * v.y + v.z * v.z + v.w * v.w;
#pragma unroll
    for (int m = 1; m < 64; m <<= 1) { s += __shfl_xor(s, m); s2 += __shfl_xor(s2, m); }
    float mu = s * (1.f / 256.f);
    float rstd = rsqrtf(s2 * (1.f / 256.f) - mu * mu + LN_EPS);
    float4 sc = *(const float4*)&ss[b * 512 + lane * 4];
    float4 sh = *(const float4*)&ss[b * 512 + 256 + lane * 4];
    int win = (b << 6) + ((hg >> 3) << 3) + (wg >> 3);
    int pos = ((hg & 7) << 3) + (wg & 7);
    ushort4 pk;
    pk.x = f2b((v.x - mu) * rstd * (1.f + sc.x) + sh.x);
    pk.y = f2b((v.y - mu) * rstd * (1.f + sc.y) + sh.y);
    pk.z = f2b((v.z - mu) * rstd * (1.f + sc.z) + sh.z);
    pk.w = f2b((v.w - mu) * rstd * (1.f + sc.w) + sh.w);
    *(ushort4*)(xw + (size_t)(win * 64 + pos) * C_ + lane * 4) = pk;
}

// ---------------- LN + modulate: one wave per token --------------------------
__global__ __launch_bounds__(256) void ln_k(const float* __restrict__ x,
                                            const float* __restrict__ ss,
                                            unsigned short* __restrict__ y_out) {
    int t = blockIdx.x * 4 + (threadIdx.x >> 6);
    int lane = threadIdx.x & 63;
    int b = t >> 12;
    float4 v = *(const float4*)&x[(size_t)t * C_ + lane * 4];
    float s = v.x + v.y + v.z + v.w;
    float s2 = v.x * v.x + v.y * v.y + v.z * v.z + v.w * v.w;
#pragma unroll
    for (int m = 1; m < 64; m <<= 1) { s += __shfl_xor(s, m); s2 += __shfl_xor(s2, m); }
    float mu = s * (1.f / 256.f);
    float rstd = rsqrtf(s2 * (1.f / 256.f) - mu * mu + LN_EPS);
    float4 sc = *(const float4*)&ss[b * 512 + lane * 4];
    float4 sh = *(const float4*)&ss[b * 512 + 256 + lane * 4];
    ushort4 pk;
    pk.x = f2b((v.x - mu) * rstd * (1.f + sc.x) + sh.x);
    pk.y = f2b((v.y - mu) * rstd * (1.f + sc.y) + sh.y);
    pk.z = f2b((v.z - mu) * rstd * (1.f + sc.z) + sh.z);
    pk.w = f2b((v.w - mu) * rstd * (1.f + sc.w) + sh.w);
    *(ushort4*)(y_out + (size_t)t * C_ + lane * 4) = pk;
}

// --------------- bf16 MFMA GEMM, 128x128 tile, BK=64, swizzled LDS -----------
// XCD-affine 1D grid (R5): all NT n-tiles of one m-tile on one XCD.
// XOR swizzle (R7): staging permutes src 16B chunk per lane (coalescing
// intact), frag reads apply quad^((l16>>1)&3) -> bank conflicts = 0.
// MINW: min waves/EU for the register allocator / occupancy.
// MODE 0: QKV -> permuted bf16 + bias; MODE 1: O-proj -> window-reverse +
// fp32 residual; MODE 2: FFN1 -> gelu bf16; MODE 3: FFN2 -> fp32 residual.
template <int KDIM, int MODE, int NT, int MINW>
__global__ __launch_bounds__(256, MINW) void gemm_bf16_k(
    const unsigned short* __restrict__ A, const unsigned short* __restrict__ Bt,
    const float* __restrict__ bias, const float* __restrict__ res,
    void* __restrict__ Cout, int Nout) {
    __shared__ __align__(16) unsigned short As[2][128 * 32];
    __shared__ __align__(16) unsigned short Bs[2][128 * 32];
    const int blk = blockIdx.x;
    const int xcd = blk & 7;
    const int idx = blk >> 3;
    const int mt = xcd + ((idx / NT) << 3);
    const int nt = idx % NT;
    const int bm = mt * 128, bn = nt * 128;
    const int tid = threadIdx.x;
    const int w = tid >> 6, lane = tid & 63;
    const int quad = lane >> 4, l16 = lane & 15;
    const int wm = (w >> 1) * 64, wn = (w & 1) * 64;
    const int srow = lane >> 2;
    const int qlog = ((lane & 3) ^ ((lane >> 3) & 3)) << 3;
    const int rsw = ((l16 >> 1) & 3) << 3;

    f32x4 acc[4][4] = {};

    for (int k0 = 0; k0 < KDIM; k0 += 64) {
        if (k0) __syncthreads();
#pragma unroll
        for (int h = 0; h < 2; ++h) {
#pragma unroll
            for (int j = 0; j < 2; ++j) {
                int r = j * 64 + w * 16 + srow;
                const unsigned short* ga = A + (size_t)(bm + r) * KDIM + k0 + h * 32 + qlog;
                unsigned short* la = &As[h][j * 2048 + w * 512 + lane * 8];
                __builtin_amdgcn_global_load_lds(
                    (const __attribute__((address_space(1))) void*)ga,
                    (__attribute__((address_space(3))) void*)la, 16, 0, 0);
                const unsigned short* gb = Bt + (size_t)(bn + r) * KDIM + k0 + h * 32 + qlog;
                unsigned short* lb = &Bs[h][j * 2048 + w * 512 + lane * 8];
                __builtin_amdgcn_global_load_lds(
                    (const __attribute__((address_space(1))) void*)gb,
                    (__attribute__((address_space(3))) void*)lb, 16, 0, 0);
            }
        }
        __syncthreads();
#pragma unroll
        for (int h = 0; h < 2; ++h) {
            bf16x8 af[4], bfr[4];
#pragma unroll
            for (int i = 0; i < 4; ++i)
                af[i] = *(const bf16x8*)&As[h][(wm + i * 16 + l16) * 32 + ((quad << 3) ^ rsw)];
#pragma unroll
            for (int j = 0; j < 4; ++j)
                bfr[j] = *(const bf16x8*)&Bs[h][(wn + j * 16 + l16) * 32 + ((quad << 3) ^ rsw)];
#pragma unroll
            for (int i = 0; i < 4; ++i)
#pragma unroll
                for (int j = 0; j < 4; ++j)
                    acc[i][j] = __builtin_amdgcn_mfma_f32_16x16x32_bf16(
                        bfr[j], af[i], acc[i][j], 0, 0, 0);
        }
    }

#pragma unroll
    for (int i = 0; i < 4; ++i) {
        const int row = bm + wm + i * 16 + l16;
        size_t rowbase = 0;
        if (MODE == 0) {
            int win = row >> 6, pos = row & 63;
            rowbase = (size_t)win * 16384 + pos * 32;
        } else if (MODE == 1) {
            int win = row >> 6, pos = row & 63;
            int b = win >> 6, wh = (win >> 3) & 7, ww = win & 7;
            int hg = (wh << 3) + (pos >> 3), wg = (ww << 3) + (pos & 7);
            int hd = (hg + SH_) & 63, wd = (wg + SH_) & 63;
            rowbase = (((size_t)b << 12) + (hd << 6) + wd) * C_;
        } else {
            rowbase = (size_t)row * Nout;
        }
#pragma unroll
        for (int j = 0; j < 4; ++j) {
            const int col = bn + wn + j * 16 + quad * 4;
            float4 bv = *(const float4*)&bias[col];
            float v0 = acc[i][j][0] + bv.x, v1 = acc[i][j][1] + bv.y;
            float v2 = acc[i][j][2] + bv.z, v3 = acc[i][j][3] + bv.w;
            if (MODE == 0) {
                int which = col >> 8, head = (col >> 5) & 7, dc = col & 31;
                ushort4 pk = {f2b(v0), f2b(v1), f2b(v2), f2b(v3)};
                *(ushort4*)((unsigned short*)Cout + (size_t)which * SL_ + rowbase +
                            head * 2048 + dc) = pk;
            } else if (MODE == 1) {
                float4 rv = *(const float4*)&res[rowbase + col];
                float4 ov = {v0 + rv.x, v1 + rv.y, v2 + rv.z, v3 + rv.w};
                *(float4*)&((float*)Cout)[rowbase + col] = ov;
            } else if (MODE == 2) {
                ushort4 pk = {f2b(gelu_f(v0)), f2b(gelu_f(v1)),
                              f2b(gelu_f(v2)), f2b(gelu_f(v3))};
                *(ushort4*)((unsigned short*)Cout + rowbase + col) = pk;
            } else {
                float4 rv = *(const float4*)&res[rowbase + col];
                float4 ov = {v0 + rv.x, v1 + rv.y, v2 + rv.z, v3 + rv.w};
                *(float4*)&((float*)Cout)[rowbase + col] = ov;
            }
        }
    }
}

// ------------- MFMA window attention: one wave per (window, head) ------------
__global__ __launch_bounds__(256) void attn_mfma_k(
    const unsigned short* __restrict__ qkv, const float* __restrict__ bias_full,
    unsigned short* __restrict__ attn_out) {
    __shared__ __align__(16) unsigned short Pb[4][64 * 66];
    __shared__ __align__(16) unsigned short Vt[4][32 * 66];
    const int w = threadIdx.x >> 6, lane = threadIdx.x & 63;
    const int wh = blockIdx.x * 4 + w;        // 0..4095
    const int win = wh >> 3, head = wh & 7;
    const int quad = lane >> 4, l16 = lane & 15;

    const unsigned short* qp = qkv + (size_t)win * 16384 + head * 2048;
    const unsigned short* kp = qp + SL_;
    const unsigned short* vp = qp + 2 * (size_t)SL_;

    // stage V transposed: Vt[d][pos]
    {
        const uint4* v4 = (const uint4*)(vp + lane * 32);
        unsigned short* dst = &Vt[w][0];
#pragma unroll
        for (int c = 0; c < 4; ++c) {
            uint4 u = v4[c];
            unsigned int uu[4] = {u.x, u.y, u.z, u.w};
#pragma unroll
            for (int p = 0; p < 4; ++p) {
                int d0 = c * 8 + p * 2;
                dst[d0 * 66 + lane] = (unsigned short)(uu[p] & 0xffff);
                dst[(d0 + 1) * 66 + lane] = (unsigned short)(uu[p] >> 16);
            }
        }
    }

    bf16x8 qf[4], kf[4];
#pragma unroll
    for (int i = 0; i < 4; ++i) {
        qf[i] = *(const bf16x8*)(qp + (i * 16 + l16) * 32 + quad * 8);
        kf[i] = *(const bf16x8*)(kp + (i * 16 + l16) * 32 + quad * 8);
    }

    f32x4 s[4][4] = {};
#pragma unroll
    for (int i = 0; i < 4; ++i)
#pragma unroll
        for (int j = 0; j < 4; ++j)
            s[i][j] = __builtin_amdgcn_mfma_f32_16x16x32_bf16(qf[i], kf[j], s[i][j], 0, 0, 0);

    const float scale = 0.17677669529663687f;
    const float* bf = bias_full + head * 4096;
    float rs[4][4];
#pragma unroll
    for (int i = 0; i < 4; ++i) {
#pragma unroll
        for (int r = 0; r < 4; ++r) {
            int row = i * 16 + quad * 4 + r;
            float acc = 0.f;
#pragma unroll
            for (int j = 0; j < 4; ++j) {
                float e = __expf(s[i][j][r] * scale + bf[row * 64 + j * 16 + l16]);
                s[i][j][r] = e;
                acc += e;
            }
#pragma unroll
            for (int msk = 1; msk < 16; msk <<= 1) acc += __shfl_xor(acc, msk);
            rs[i][r] = 1.f / acc;
        }
    }

#pragma unroll
    for (int i = 0; i < 4; ++i)
#pragma unroll
        for (int j = 0; j < 4; ++j)
#pragma unroll
            for (int r = 0; r < 4; ++r)
                Pb[w][(i * 16 + quad * 4 + r) * 66 + j * 16 + l16] = f2b(s[i][j][r]);

    __syncthreads();

    f32x4 o[4][2] = {};
#pragma unroll
    for (int st = 0; st < 2; ++st) {
        bf16x8 bv[2];
#pragma unroll
        for (int jo = 0; jo < 2; ++jo)
            bv[jo] = *(const bf16x8*)&Vt[w][(jo * 16 + l16) * 66 + st * 32 + quad * 8];
#pragma unroll
        for (int i = 0; i < 4; ++i) {
            bf16x8 af = *(const bf16x8*)&Pb[w][(i * 16 + l16) * 66 + st * 32 + quad * 8];
#pragma unroll
            for (int jo = 0; jo < 2; ++jo)
                o[i][jo] = __builtin_amdgcn_mfma_f32_16x16x32_bf16(af, bv[jo], o[i][jo], 0, 0, 0);
        }
    }

#pragma unroll
    for (int i = 0; i < 4; ++i)
#pragma unroll
        for (int jo = 0; jo < 2; ++jo)
#pragma unroll
            for (int r = 0; r < 4; ++r) {
                int row = i * 16 + quad * 4 + r;
                int d = jo * 16 + l16;
                attn_out[((size_t)(win * 64 + row)) * C_ + head * 32 + d] =
                    f2b(o[i][jo][r] * rs[i][r]);
            }
}

extern "C" void kernel_launch(void* const* d_in, const int* in_sizes, int n_in,
                              void* d_out, int out_size, void* d_ws, size_t ws_size,
                              hipStream_t stream) {
    const float* x        = (const float*)d_in[0];
    const float* t_embed  = (const float*)d_in[1];
    const float* adaln1_w = (const float*)d_in[4];
    const float* adaln1_b = (const float*)d_in[5];
    const float* adaln2_w = (const float*)d_in[6];
    const float* adaln2_b = (const float*)d_in[7];
    const float* bt       = (const float*)d_in[8];
    const float* q_w = (const float*)d_in[9],  *q_b = (const float*)d_in[10];
    const float* k_w = (const float*)d_in[11], *k_b = (const float*)d_in[12];
    const float* v_w = (const float*)d_in[13], *v_b = (const float*)d_in[14];
    const float* o_w = (const float*)d_in[15], *o_b = (const float*)d_in[16];
    const float* f1_w = (const float*)d_in[17], *f1_b = (const float*)d_in[18];
    const float* f2_w = (const float*)d_in[19], *f2_b = (const float*)d_in[20];
    float* out = (float*)d_out;

    char* wsb = (char*)d_ws;
    float* ss1            = (float*)(wsb + 0);
    float* ss2            = (float*)(wsb + 16384);
    float* qkvB           = (float*)(wsb + 32768);
    unsigned short* qkvT  = (unsigned short*)(wsb + 36864);
    unsigned short* oT    = (unsigned short*)(wsb + 430080);
    unsigned short* f1T   = (unsigned short*)(wsb + 561152);
    unsigned short* f2T   = (unsigned short*)(wsb + 1085440);
    float* bias_full      = (float*)(wsb + 1609728);               // 131072 B
    unsigned short* xw    = (unsigned short*)(wsb + 2097152);      // [M][256] bf16
    unsigned short* qkv   = (unsigned short*)(wsb + 18874368);     // 3 x SL_ bf16
    unsigned short* attn  = (unsigned short*)(wsb + 69206016);     // [M][256] bf16
    unsigned short* xn2   = xw;                                    // reuse
    unsigned short* hbuf  = qkv;                                   // reuse (67.1 MB)
    float* x1             = (float*)(wsb + 85983232);              // [M][256] fp32

    prep_k<<<3235, 256, 0, stream>>>(q_w, k_w, v_w, o_w, f1_w, f2_w, q_b, k_b, v_b, bt,
                                     t_embed, adaln1_w, adaln1_b, adaln2_w, adaln2_b,
                                     qkvT, oT, f1T, f2T, qkvB, bias_full, ss1, ss2);
    ln_win_k<<<8192, 256, 0, stream>>>(x, ss1, xw);

    gemm_bf16_k<256, 0, 6, 3><<<1536, 256, 0, stream>>>(xw, qkvT, qkvB, nullptr, qkv, 768);

    attn_mfma_k<<<1024, 256, 0, stream>>>(qkv, bias_full, attn);

    gemm_bf16_k<256, 1, 2, 1><<<512, 256, 0, stream>>>(attn, oT, o_b, x, x1, 256);
    ln_k<<<8192, 256, 0, stream>>>(x1, ss2, xn2);
    gemm_bf16_k<256, 2, 8, 3><<<2048, 256, 0, stream>>>(xn2, f1T, f1_b, nullptr, hbuf, 1024);
    gemm_bf16_k<1024, 3, 2, 1><<<512, 256, 0, stream>>>(hbuf, f2T, f2_b, x1, out, 256);
}